// Round 1
// baseline (165.516 us; speedup 1.0000x reference)
//
#include <hip/hip_runtime.h>

#define T_ 2
#define N_ 4096
#define E_ 4096
#define D_ 128
#define NL_ 2
#define CAP 64   // max nnz per row/col we store; Binomial(4096,0.002) mean 8.2 -> P(>64) ~ 0

// ---------------------------------------------------------------------------
// init: xcur = nodeacc = x ; revacc = 0 ; cntEN = 0
__global__ void k_init(const float* __restrict__ x, float* __restrict__ xcur,
                       float* __restrict__ nodeacc, float* __restrict__ revacc,
                       int* __restrict__ cntEN) {
    int i = blockIdx.x * 256 + threadIdx.x;   // grid covers N_*D_ = 524288
    float v = x[i];
    xcur[i] = v;
    nodeacc[i] = v;
    revacc[i] = 0.0f;   // E_*D_ == N_*D_
    if (i < T_ * E_) cntEN[i] = 0;
}

// ---------------------------------------------------------------------------
// build: one pass over H. Per (t,n) row: ordered compaction of nonzero edge ids
// into adjNE (deterministic), atomic append of n into adjEN (sorted later),
// degree counts -> dVis.
__global__ void k_build(const float* __restrict__ H, float* __restrict__ dVis,
                        int* __restrict__ cntNE, int* __restrict__ adjNE,
                        int* __restrict__ cntEN, int* __restrict__ adjEN) {
    int bid = blockIdx.x;          // t*N + n
    int t = bid >> 12;             // N_ = 4096
    int tid = threadIdx.x;
    int wid = tid >> 6, lane = tid & 63;
    __shared__ int s_w[4];
    const float* row = H + (size_t)bid * E_;
    int* adjrow = adjNE + (size_t)bid * CAP;
    int total = 0;
    for (int c = 0; c < E_ / 256; ++c) {
        int e = c * 256 + tid;
        float v = row[e];
        bool p = (v != 0.0f);
        unsigned long long ball = __ballot(p);
        int wcnt = __popcll(ball);
        if (lane == 0) s_w[wid] = wcnt;
        __syncthreads();
        int wpre = 0;
        #pragma unroll
        for (int w = 0; w < 4; ++w) { if (w < wid) wpre += s_w[w]; }
        int chunk = s_w[0] + s_w[1] + s_w[2] + s_w[3];
        if (p) {
            int pos = total + wpre + __popcll(ball & ((1ull << lane) - 1ull));
            if (pos < CAP) adjrow[pos] = e;
            int slot = atomicAdd(&cntEN[t * E_ + e], 1);
            if (slot < CAP) adjEN[((size_t)(t * E_ + e)) * CAP + slot] = bid & (N_ - 1);
        }
        total += chunk;
        __syncthreads();
    }
    if (tid == 0) {
        cntNE[bid] = total < CAP ? total : CAP;
        dVis[bid] = total > 0 ? rsqrtf((float)total) : 0.0f;
    }
}

// ---------------------------------------------------------------------------
// finalize: clamp+store edge counts, dEinv, sort each adjEN row (determinism)
__global__ void k_finalize(float* __restrict__ dEinv, int* __restrict__ cntEN,
                           int* __restrict__ adjEN) {
    int i = blockIdx.x * 256 + threadIdx.x;   // T_*E_
    int c = cntEN[i];
    if (c > CAP) c = CAP;
    cntEN[i] = c;
    dEinv[i] = c > 0 ? 1.0f / (float)c : 0.0f;
    int* row = adjEN + (size_t)i * CAP;
    for (int a = 1; a < c; ++a) {
        int key = row[a];
        int b = a - 1;
        while (b >= 0 && row[b] > key) { row[b + 1] = row[b]; --b; }
        row[b + 1] = key;
    }
}

// ---------------------------------------------------------------------------
// xw: y[t,n,:] = dVis[t,n] * (x[n,:] @ W[l,t]^T + b[l,t,:])
// block = 256 threads handles (t, 32 nodes); W[l,t] transposed into LDS.
__global__ __launch_bounds__(256) void k_xw(const float* __restrict__ x,
                                            const float* __restrict__ W,
                                            const float* __restrict__ b,
                                            const float* __restrict__ dVis,
                                            float* __restrict__ y, int l) {
    int t = blockIdx.y;
    int n0 = blockIdx.x * 32;
    int tid = threadIdx.x;
    __shared__ float Wt[128 * 132];   // Wt[k*132 + o] = W[l,t,o,k]; pad 132 (16B-aligned rows)
    __shared__ float xs[32 * 132];    // xs[j*132 + k] = x[n0+j, k]
    const float* Wg = W + ((size_t)l * T_ + t) * D_ * D_;
    for (int i = tid; i < D_ * D_; i += 256) {
        int o = i >> 7, k = i & 127;
        Wt[k * 132 + o] = Wg[i];
    }
    for (int i = tid; i < 32 * D_; i += 256) {
        int j = i >> 7, k = i & 127;
        xs[j * 132 + k] = x[(size_t)(n0 + j) * D_ + k];
    }
    __syncthreads();
    int d0 = (tid & 31) * 4;
    int j0 = (tid >> 5) * 4;
    float acc[4][4] = {};
    for (int k4 = 0; k4 < 32; ++k4) {
        float4 xv[4];
        #pragma unroll
        for (int jj = 0; jj < 4; ++jj)
            xv[jj] = *reinterpret_cast<const float4*>(&xs[(j0 + jj) * 132 + k4 * 4]);
        #pragma unroll
        for (int kk = 0; kk < 4; ++kk) {
            float4 wv = *reinterpret_cast<const float4*>(&Wt[(k4 * 4 + kk) * 132 + d0]);
            #pragma unroll
            for (int jj = 0; jj < 4; ++jj) {
                float xsv = (kk == 0) ? xv[jj].x : (kk == 1) ? xv[jj].y : (kk == 2) ? xv[jj].z : xv[jj].w;
                acc[jj][0] += xsv * wv.x;
                acc[jj][1] += xsv * wv.y;
                acc[jj][2] += xsv * wv.z;
                acc[jj][3] += xsv * wv.w;
            }
        }
    }
    const float* bg = b + ((size_t)l * T_ + t) * D_;
    float b0 = bg[d0], b1 = bg[d0 + 1], b2 = bg[d0 + 2], b3 = bg[d0 + 3];
    #pragma unroll
    for (int jj = 0; jj < 4; ++jj) {
        int n = n0 + j0 + jj;
        float s = dVis[t * N_ + n];
        float4 o;
        o.x = s * (acc[jj][0] + b0);
        o.y = s * (acc[jj][1] + b1);
        o.z = s * (acc[jj][2] + b2);
        o.w = s * (acc[jj][3] + b3);
        *reinterpret_cast<float4*>(&y[((size_t)(t * N_ + n)) * D_ + d0]) = o;
    }
}

// ---------------------------------------------------------------------------
// ye[t,e,:] = dEinv[t,e] * sum_{n in adjEN[t,e]} y[t,n,:]
__global__ void k_ye(const float* __restrict__ y, const float* __restrict__ dEinv,
                     const int* __restrict__ cntEN, const int* __restrict__ adjEN,
                     float* __restrict__ ye) {
    int bid = blockIdx.x;   // t*E + e
    int d = threadIdx.x;    // 128
    int t = bid >> 12;
    int c = cntEN[bid];
    const int* row = adjEN + (size_t)bid * CAP;
    float s = 0.0f;
    for (int j = 0; j < c; ++j) {
        int n = row[j];
        s += y[((size_t)(t * N_) + n) * D_ + d];
    }
    ye[(size_t)bid * D_ + d] = dEinv[bid] * s;
}

// ---------------------------------------------------------------------------
// e[t,n,:] = leaky(dVis[t,n] * sum_{e in adjNE[t,n]} ye[t,e,:]);
// xcur[n,:] = sum_t e ; nodeacc += xcur ; (last) out = nodeacc/3
__global__ void k_e(const float* __restrict__ yebuf, const float* __restrict__ dVis,
                    const int* __restrict__ cntNE, const int* __restrict__ adjNE,
                    float* __restrict__ ebuf, float* __restrict__ xcur,
                    float* __restrict__ nodeacc, float* __restrict__ outnode, int last) {
    int n = blockIdx.x;
    int d = threadIdx.x;
    float xnew = 0.0f;
    #pragma unroll
    for (int t = 0; t < T_; ++t) {
        int r = t * N_ + n;
        int c = cntNE[r];
        const int* row = adjNE + (size_t)r * CAP;
        float s = 0.0f;
        for (int j = 0; j < c; ++j)
            s += yebuf[((size_t)(t * E_) + row[j]) * D_ + d];
        float ev = dVis[r] * s;
        ev = ev >= 0.0f ? ev : 0.01f * ev;
        ebuf[(size_t)r * D_ + d] = ev;
        xnew += ev;
    }
    size_t i = (size_t)n * D_ + d;
    xcur[i] = xnew;
    float na = nodeacc[i] + xnew;
    nodeacc[i] = na;
    if (last) outnode[i] = na * (1.0f / 3.0f);
}

// ---------------------------------------------------------------------------
// o[e,:] accumulation: revacc += sum_t dEinv[t,e] * sum_{n in adjEN[t,e]} e[t,n,:]
__global__ void k_o(const float* __restrict__ ebuf, const float* __restrict__ dEinv,
                    const int* __restrict__ cntEN, const int* __restrict__ adjEN,
                    float* __restrict__ revacc, float* __restrict__ outrev, int last) {
    int e = blockIdx.x;
    int d = threadIdx.x;
    float acc = 0.0f;
    #pragma unroll
    for (int t = 0; t < T_; ++t) {
        int r = t * E_ + e;
        int c = cntEN[r];
        const int* row = adjEN + (size_t)r * CAP;
        float s = 0.0f;
        for (int j = 0; j < c; ++j)
            s += ebuf[((size_t)(t * N_) + row[j]) * D_ + d];
        acc += dEinv[r] * s;
    }
    size_t i = (size_t)e * D_ + d;
    float ra = revacc[i] + acc;
    revacc[i] = ra;
    if (last) outrev[i] = ra * 0.5f;
}

// ---------------------------------------------------------------------------
extern "C" void kernel_launch(void* const* d_in, const int* in_sizes, int n_in,
                              void* d_out, int out_size, void* d_ws, size_t ws_size,
                              hipStream_t stream) {
    const float* x = (const float*)d_in[0];
    const float* H = (const float*)d_in[1];
    const float* W = (const float*)d_in[2];
    const float* b = (const float*)d_in[3];
    float* out = (float*)d_out;

    char* p = (char*)d_ws;
    auto alloc = [&](size_t bytes) {
        char* r = p;
        p += (bytes + 255) & ~(size_t)255;
        return r;
    };
    float* dVis    = (float*)alloc((size_t)T_ * N_ * 4);
    float* dEinv   = (float*)alloc((size_t)T_ * E_ * 4);
    int*   cntNE   = (int*)  alloc((size_t)T_ * N_ * 4);
    int*   cntEN   = (int*)  alloc((size_t)T_ * E_ * 4);
    int*   adjNE   = (int*)  alloc((size_t)T_ * N_ * CAP * 4);
    int*   adjEN   = (int*)  alloc((size_t)T_ * E_ * CAP * 4);
    float* y       = (float*)alloc((size_t)T_ * N_ * D_ * 4);
    float* yebuf   = (float*)alloc((size_t)T_ * E_ * D_ * 4);
    float* ebuf    = (float*)alloc((size_t)T_ * N_ * D_ * 4);
    float* xcur    = (float*)alloc((size_t)N_ * D_ * 4);
    float* nodeacc = (float*)alloc((size_t)N_ * D_ * 4);
    float* revacc  = (float*)alloc((size_t)E_ * D_ * 4);

    k_init<<<(N_ * D_) / 256, 256, 0, stream>>>(x, xcur, nodeacc, revacc, cntEN);
    k_build<<<T_ * N_, 256, 0, stream>>>(H, dVis, cntNE, adjNE, cntEN, adjEN);
    k_finalize<<<(T_ * E_) / 256, 256, 0, stream>>>(dEinv, cntEN, adjEN);

    for (int l = 0; l < NL_; ++l) {
        int last = (l == NL_ - 1);
        k_xw<<<dim3(N_ / 32, T_), 256, 0, stream>>>(xcur, W, b, dVis, y, l);
        k_ye<<<T_ * E_, 128, 0, stream>>>(y, dEinv, cntEN, adjEN, yebuf);
        k_e<<<N_, 128, 0, stream>>>(yebuf, dVis, cntNE, adjNE, ebuf, xcur, nodeacc, out, last);
        k_o<<<E_, 128, 0, stream>>>(ebuf, dEinv, cntEN, adjEN, revacc, out + (size_t)N_ * D_, last);
    }
}

// Round 2
// 155.757 us; speedup vs baseline: 1.0627x; 1.0627x over previous
//
#include <hip/hip_runtime.h>

#define T_ 2
#define N_ 4096
#define E_ 4096
#define D_ 128
#define NL_ 2
#define CAP 64   // max nnz per row/col we store; Binomial(4096,0.002) mean 8.2 -> P(>64) ~ 0

// ---------------------------------------------------------------------------
// init: xcur = nodeacc = x ; revacc = 0 ; cntEN = 0
__global__ void k_init(const float* __restrict__ x, float* __restrict__ xcur,
                       float* __restrict__ nodeacc, float* __restrict__ revacc,
                       int* __restrict__ cntEN) {
    int i = blockIdx.x * 256 + threadIdx.x;   // grid covers N_*D_ = 524288
    float v = x[i];
    xcur[i] = v;
    nodeacc[i] = v;
    revacc[i] = 0.0f;   // E_*D_ == N_*D_
    if (i < T_ * E_) cntEN[i] = 0;
}

// ---------------------------------------------------------------------------
// build: one pass over H, one block per (t,n) row, single-shot.
// Each thread reads 16 floats (4 lane-coalesced float4 loads), builds a 16-bit
// mask, block-wide exclusive prefix-sum gives the adjNE write offset
// (deterministic order). Edge-side lists via atomic append (sorted later).
__global__ __launch_bounds__(256) void k_build(const float* __restrict__ H,
                        float* __restrict__ dVis,
                        int* __restrict__ cntNE, int* __restrict__ adjNE,
                        int* __restrict__ cntEN, int* __restrict__ adjEN) {
    int bid = blockIdx.x;          // t*N + n
    int t = bid >> 12;             // N_ = 4096
    int tid = threadIdx.x;
    int lane = tid & 63, wid = tid >> 6;
    const float4* row4 = (const float4*)(H + (size_t)bid * E_);
    float4 v[4];
    #pragma unroll
    for (int i = 0; i < 4; ++i) v[i] = row4[i * 256 + tid];   // lane-coalesced, 1KB/instr
    unsigned mask = 0;
    #pragma unroll
    for (int i = 0; i < 4; ++i) {
        if (v[i].x != 0.0f) mask |= 1u << (i * 4 + 0);
        if (v[i].y != 0.0f) mask |= 1u << (i * 4 + 1);
        if (v[i].z != 0.0f) mask |= 1u << (i * 4 + 2);
        if (v[i].w != 0.0f) mask |= 1u << (i * 4 + 3);
    }
    int cnt = __popc(mask);
    // wave-inclusive scan (64 lanes)
    int incl = cnt;
    #pragma unroll
    for (int off = 1; off < 64; off <<= 1) {
        int u = __shfl_up(incl, off);
        if (lane >= off) incl += u;
    }
    __shared__ int wsum[4];
    if (lane == 63) wsum[wid] = incl;
    __syncthreads();
    int wbase = 0;
    #pragma unroll
    for (int w = 0; w < 4; ++w) if (w < wid) wbase += wsum[w];
    int pos = wbase + incl - cnt;  // exclusive prefix across block
    int* adjrow = adjNE + (size_t)bid * CAP;
    int n_id = bid & (N_ - 1);
    unsigned m = mask;
    while (m) {
        int bpos = __ffs((int)m) - 1;
        m &= m - 1;
        int i = bpos >> 2, j = bpos & 3;
        int e = (i * 256 + tid) * 4 + j;
        if (pos < CAP) adjrow[pos] = e;
        ++pos;
        int slot = atomicAdd(&cntEN[t * E_ + e], 1);
        if (slot < CAP) adjEN[((size_t)(t * E_ + e)) * CAP + slot] = n_id;
    }
    if (tid == 255) {   // lane 63 of wave 3: wbase+incl == block total
        int total = wbase + incl;
        cntNE[bid] = total < CAP ? total : CAP;
        dVis[bid] = total > 0 ? rsqrtf((float)total) : 0.0f;
    }
}

// ---------------------------------------------------------------------------
// finalize: clamp+store edge counts, dEinv, sort each adjEN row (determinism)
__global__ void k_finalize(float* __restrict__ dEinv, int* __restrict__ cntEN,
                           int* __restrict__ adjEN) {
    int i = blockIdx.x * 256 + threadIdx.x;   // T_*E_
    int c = cntEN[i];
    if (c > CAP) c = CAP;
    cntEN[i] = c;
    dEinv[i] = c > 0 ? 1.0f / (float)c : 0.0f;
    int* row = adjEN + (size_t)i * CAP;
    for (int a = 1; a < c; ++a) {
        int key = row[a];
        int b = a - 1;
        while (b >= 0 && row[b] > key) { row[b + 1] = row[b]; --b; }
        row[b + 1] = key;
    }
}

// ---------------------------------------------------------------------------
// xw: y[t,n,:] = dVis[t,n] * (x[n,:] @ W[l,t]^T + b[l,t,:])
// block = 256 threads handles (t, 32 nodes); W[l,t] transposed into LDS.
__global__ __launch_bounds__(256) void k_xw(const float* __restrict__ x,
                                            const float* __restrict__ W,
                                            const float* __restrict__ b,
                                            const float* __restrict__ dVis,
                                            float* __restrict__ y, int l) {
    int t = blockIdx.y;
    int n0 = blockIdx.x * 32;
    int tid = threadIdx.x;
    __shared__ float Wt[128 * 132];   // Wt[k*132 + o] = W[l,t,o,k]; pad 132
    __shared__ float xs[32 * 132];    // xs[j*132 + k] = x[n0+j, k]
    const float* Wg = W + ((size_t)l * T_ + t) * D_ * D_;
    for (int i = tid; i < D_ * D_; i += 256) {
        int o = i >> 7, k = i & 127;
        Wt[k * 132 + o] = Wg[i];
    }
    for (int i = tid; i < 32 * D_; i += 256) {
        int j = i >> 7, k = i & 127;
        xs[j * 132 + k] = x[(size_t)(n0 + j) * D_ + k];
    }
    __syncthreads();
    int d0 = (tid & 31) * 4;
    int j0 = (tid >> 5) * 4;
    float acc[4][4] = {};
    for (int k4 = 0; k4 < 32; ++k4) {
        float4 xv[4];
        #pragma unroll
        for (int jj = 0; jj < 4; ++jj)
            xv[jj] = *reinterpret_cast<const float4*>(&xs[(j0 + jj) * 132 + k4 * 4]);
        #pragma unroll
        for (int kk = 0; kk < 4; ++kk) {
            float4 wv = *reinterpret_cast<const float4*>(&Wt[(k4 * 4 + kk) * 132 + d0]);
            #pragma unroll
            for (int jj = 0; jj < 4; ++jj) {
                float xsv = (kk == 0) ? xv[jj].x : (kk == 1) ? xv[jj].y : (kk == 2) ? xv[jj].z : xv[jj].w;
                acc[jj][0] += xsv * wv.x;
                acc[jj][1] += xsv * wv.y;
                acc[jj][2] += xsv * wv.z;
                acc[jj][3] += xsv * wv.w;
            }
        }
    }
    const float* bg = b + ((size_t)l * T_ + t) * D_;
    float b0 = bg[d0], b1 = bg[d0 + 1], b2 = bg[d0 + 2], b3 = bg[d0 + 3];
    #pragma unroll
    for (int jj = 0; jj < 4; ++jj) {
        int n = n0 + j0 + jj;
        float s = dVis[t * N_ + n];
        float4 o;
        o.x = s * (acc[jj][0] + b0);
        o.y = s * (acc[jj][1] + b1);
        o.z = s * (acc[jj][2] + b2);
        o.w = s * (acc[jj][3] + b3);
        *reinterpret_cast<float4*>(&y[((size_t)(t * N_ + n)) * D_ + d0]) = o;
    }
}

// ---------------------------------------------------------------------------
// ye[t,e,:] = dEinv[t,e] * sum_{n in adjEN[t,e]} y[t,n,:]   (2 rows / block)
__global__ __launch_bounds__(256) void k_ye(const float* __restrict__ y,
                     const float* __restrict__ dEinv,
                     const int* __restrict__ cntEN, const int* __restrict__ adjEN,
                     float* __restrict__ ye) {
    int bid = blockIdx.x * 2 + (threadIdx.x >> 7);   // t*E + e
    int d = threadIdx.x & 127;
    int t = bid >> 12;
    int c = cntEN[bid];
    const int* row = adjEN + (size_t)bid * CAP;
    const float* src = y + (size_t)(t * N_) * D_;
    float s = 0.0f;
    for (int j0 = 0; j0 < c; j0 += 4) {
        int4 ids = *reinterpret_cast<const int4*>(row + j0);
        s += src[(size_t)ids.x * D_ + d];
        if (j0 + 1 < c) s += src[(size_t)ids.y * D_ + d];
        if (j0 + 2 < c) s += src[(size_t)ids.z * D_ + d];
        if (j0 + 3 < c) s += src[(size_t)ids.w * D_ + d];
    }
    ye[(size_t)bid * D_ + d] = dEinv[bid] * s;
}

// ---------------------------------------------------------------------------
// e[t,n,:] = leaky(dVis[t,n] * sum_{e in adjNE[t,n]} ye[t,e,:]);
// xcur[n,:] = sum_t e ; nodeacc += xcur ; (last) out = nodeacc/3  (2 nodes/block)
__global__ __launch_bounds__(256) void k_e(const float* __restrict__ yebuf,
                    const float* __restrict__ dVis,
                    const int* __restrict__ cntNE, const int* __restrict__ adjNE,
                    float* __restrict__ ebuf, float* __restrict__ xcur,
                    float* __restrict__ nodeacc, float* __restrict__ outnode, int last) {
    int n = blockIdx.x * 2 + (threadIdx.x >> 7);
    int d = threadIdx.x & 127;
    float xnew = 0.0f;
    #pragma unroll
    for (int t = 0; t < T_; ++t) {
        int r = t * N_ + n;
        int c = cntNE[r];
        const int* row = adjNE + (size_t)r * CAP;
        const float* src = yebuf + (size_t)(t * E_) * D_;
        float s = 0.0f;
        for (int j0 = 0; j0 < c; j0 += 4) {
            int4 ids = *reinterpret_cast<const int4*>(row + j0);
            s += src[(size_t)ids.x * D_ + d];
            if (j0 + 1 < c) s += src[(size_t)ids.y * D_ + d];
            if (j0 + 2 < c) s += src[(size_t)ids.z * D_ + d];
            if (j0 + 3 < c) s += src[(size_t)ids.w * D_ + d];
        }
        float ev = dVis[r] * s;
        ev = ev >= 0.0f ? ev : 0.01f * ev;
        ebuf[(size_t)r * D_ + d] = ev;
        xnew += ev;
    }
    size_t i = (size_t)n * D_ + d;
    xcur[i] = xnew;
    float na = nodeacc[i] + xnew;
    nodeacc[i] = na;
    if (last) outnode[i] = na * (1.0f / 3.0f);
}

// ---------------------------------------------------------------------------
// o[e,:] accumulation: revacc += sum_t dEinv[t,e] * sum_{n in adjEN[t,e]} e[t,n,:]
__global__ __launch_bounds__(256) void k_o(const float* __restrict__ ebuf,
                    const float* __restrict__ dEinv,
                    const int* __restrict__ cntEN, const int* __restrict__ adjEN,
                    float* __restrict__ revacc, float* __restrict__ outrev, int last) {
    int e = blockIdx.x * 2 + (threadIdx.x >> 7);
    int d = threadIdx.x & 127;
    float acc = 0.0f;
    #pragma unroll
    for (int t = 0; t < T_; ++t) {
        int r = t * E_ + e;
        int c = cntEN[r];
        const int* row = adjEN + (size_t)r * CAP;
        const float* src = ebuf + (size_t)(t * N_) * D_;
        float s = 0.0f;
        for (int j0 = 0; j0 < c; j0 += 4) {
            int4 ids = *reinterpret_cast<const int4*>(row + j0);
            s += src[(size_t)ids.x * D_ + d];
            if (j0 + 1 < c) s += src[(size_t)ids.y * D_ + d];
            if (j0 + 2 < c) s += src[(size_t)ids.z * D_ + d];
            if (j0 + 3 < c) s += src[(size_t)ids.w * D_ + d];
        }
        acc += dEinv[r] * s;
    }
    size_t i = (size_t)e * D_ + d;
    float ra = revacc[i] + acc;
    revacc[i] = ra;
    if (last) outrev[i] = ra * 0.5f;
}

// ---------------------------------------------------------------------------
extern "C" void kernel_launch(void* const* d_in, const int* in_sizes, int n_in,
                              void* d_out, int out_size, void* d_ws, size_t ws_size,
                              hipStream_t stream) {
    const float* x = (const float*)d_in[0];
    const float* H = (const float*)d_in[1];
    const float* W = (const float*)d_in[2];
    const float* b = (const float*)d_in[3];
    float* out = (float*)d_out;

    char* p = (char*)d_ws;
    auto alloc = [&](size_t bytes) {
        char* r = p;
        p += (bytes + 255) & ~(size_t)255;
        return r;
    };
    float* dVis    = (float*)alloc((size_t)T_ * N_ * 4);
    float* dEinv   = (float*)alloc((size_t)T_ * E_ * 4);
    int*   cntNE   = (int*)  alloc((size_t)T_ * N_ * 4);
    int*   cntEN   = (int*)  alloc((size_t)T_ * E_ * 4);
    int*   adjNE   = (int*)  alloc((size_t)T_ * N_ * CAP * 4);
    int*   adjEN   = (int*)  alloc((size_t)T_ * E_ * CAP * 4);
    float* y       = (float*)alloc((size_t)T_ * N_ * D_ * 4);
    float* yebuf   = (float*)alloc((size_t)T_ * E_ * D_ * 4);
    float* ebuf    = (float*)alloc((size_t)T_ * N_ * D_ * 4);
    float* xcur    = (float*)alloc((size_t)N_ * D_ * 4);
    float* nodeacc = (float*)alloc((size_t)N_ * D_ * 4);
    float* revacc  = (float*)alloc((size_t)E_ * D_ * 4);

    k_init<<<(N_ * D_) / 256, 256, 0, stream>>>(x, xcur, nodeacc, revacc, cntEN);
    k_build<<<T_ * N_, 256, 0, stream>>>(H, dVis, cntNE, adjNE, cntEN, adjEN);
    k_finalize<<<(T_ * E_) / 256, 256, 0, stream>>>(dEinv, cntEN, adjEN);

    for (int l = 0; l < NL_; ++l) {
        int last = (l == NL_ - 1);
        k_xw<<<dim3(N_ / 32, T_), 256, 0, stream>>>(xcur, W, b, dVis, y, l);
        k_ye<<<T_ * E_ / 2, 256, 0, stream>>>(y, dEinv, cntEN, adjEN, yebuf);
        k_e<<<N_ / 2, 256, 0, stream>>>(yebuf, dVis, cntNE, adjNE, ebuf, xcur, nodeacc, out, last);
        k_o<<<E_ / 2, 256, 0, stream>>>(ebuf, dEinv, cntEN, adjEN, revacc, out + (size_t)N_ * D_, last);
    }
}